// Round 1
// 365.025 us; speedup vs baseline: 1.0411x; 1.0411x over previous
//
#include <hip/hip_runtime.h>

#define NN 100000
#define NE 1600000
#define NBUCK 1563     // ceil(NN/64)
#define NBH 256        // histogram/placement blocks
#define CHUNK 6250     // NE/NBH
#define NBXB 12500     // NN*32/256 blocks for x->bf16
#define NBG 1563       // ceil(NN/64) for fused GEMM

// ws layout (bytes):
//   xb:    0           (25,600,000)  bf16 x                      [live: k_pre..k_agg1]
//   P:     25,600,000  (25,600,000)  per-node 256B slot          [live: k_agg1..k_agg2]
//     ghist: 25,600,000 (1,600,512)  [NBH][NBUCK]  dead after k_scanB   (overlaps P)
//     boffT: 27,200,512 (1,600,512)  [NBUCK][NBH]  dead after k_place   (overlaps P)
//     tot:   28,801,024 (6,252)      dead after k_binC                  (overlaps P)
//     bbase: 28,807,276 (6,252)      dead after k_binC                  (overlaps P)
//   row_start: 51,200,000 ((NN+1)*4)
//   dinv:  51,600,004  (400,000)
//   csr:   52,000,004  (6,400,000)   node-sorted src-only
//   ebuf:  58,400,004  (6,400,000)   bucket-sorted packed; dead after k_binC
// total 64.8 MB (< previous 66.4 MB footprint). No memsets needed.

typedef short bf16x8 __attribute__((ext_vector_type(8)));
typedef float f32x4  __attribute__((ext_vector_type(4)));
typedef float f32x2  __attribute__((ext_vector_type(2)));

__device__ __forceinline__ float b2f(unsigned short u) {
    return __uint_as_float(((unsigned int)u) << 16);
}
__device__ __forceinline__ unsigned short f2b(float f) {
    unsigned int x = __float_as_uint(f);
    x += 0x7FFFu + ((x >> 16) & 1u);   // RNE
    return (unsigned short)(x >> 16);
}

// ---- fused: x->bf16 (blocks [0,NBXB)) + bucket histogram (blocks [NBXB,NBXB+NBH)) ----
__global__ __launch_bounds__(256) void k_pre(const float* __restrict__ x,
                                             unsigned short* __restrict__ xb,
                                             const int* __restrict__ dst,
                                             int* __restrict__ ghist) {
    int b = blockIdx.x;
    if (b < NBXB) {
        int id = b * 256 + threadIdx.x;
        float4 v = ((const float4*)x)[id];
        ushort4 o;
        o.x = f2b(v.x); o.y = f2b(v.y); o.z = f2b(v.z); o.w = f2b(v.w);
        ((ushort4*)xb)[id] = o;
        return;
    }
    __shared__ int h[NBUCK];
    int tid = threadIdx.x;
    int i = b - NBXB;
    for (int k = tid; k < NBUCK; k += 256) h[k] = 0;
    __syncthreads();
    int e0 = i * CHUNK;
    for (int e = e0 + tid; e < e0 + CHUNK; e += 256) {
        unsigned d = (unsigned)dst[e];
        if (d < NN) atomicAdd(&h[d >> 6], 1);
    }
    __syncthreads();
    for (int k = tid; k < NBUCK; k += 256) ghist[i * NBUCK + k] = h[k];
}

// ---- per-bucket scan over blocks: boffT[k][i], tot[k] ----
__global__ __launch_bounds__(256) void k_scanB(const int* __restrict__ ghist,
                                               int* __restrict__ boffT,
                                               int* __restrict__ tot) {
    int k = blockIdx.x * 256 + threadIdx.x;
    if (k >= NBUCK) return;
    int sum = 0;
#pragma unroll 8
    for (int i = 0; i < NBH; ++i) {
        int c = ghist[i * NBUCK + k];
        boffT[k * NBH + i] = sum;
        sum += c;
    }
    tot[k] = sum;
}

// ---- exclusive scan of bucket totals -> bbase ----
__global__ __launch_bounds__(256) void k_scanT(const int* __restrict__ tot,
                                               int* __restrict__ bbase) {
    __shared__ int s[256];
    int tid = threadIdx.x;
    int k0 = tid * 7;
    int v[7]; int S = 0;
#pragma unroll
    for (int q = 0; q < 7; ++q) {
        int k = k0 + q;
        v[q] = (k < NBUCK) ? tot[k] : 0;
        S += v[q];
    }
    s[tid] = S;
    __syncthreads();
    for (int off = 1; off < 256; off <<= 1) {
        int t = (tid >= off) ? s[tid - off] : 0;
        __syncthreads();
        s[tid] += t;
        __syncthreads();
    }
    int run = s[tid] - S;   // exclusive
#pragma unroll
    for (int q = 0; q < 7; ++q) {
        int k = k0 + q;
        if (k < NBUCK) { bbase[k] = run; run += v[q]; }
    }
}

// ---- placement: bucket-sorted packed records via LDS cursors (no global atomics) ----
__global__ __launch_bounds__(256) void k_place(const int* __restrict__ src,
                                               const int* __restrict__ dst,
                                               const int* __restrict__ bbase,
                                               const int* __restrict__ boffT,
                                               int* __restrict__ ebuf) {
    __shared__ int cur[NBUCK];
    int tid = threadIdx.x, i = blockIdx.x;
    for (int k = tid; k < NBUCK; k += 256) cur[k] = bbase[k] + boffT[k * NBH + i];
    __syncthreads();
    int e0 = i * CHUNK;
    for (int e = e0 + tid; e < e0 + CHUNK; e += 256) {
        unsigned d = (unsigned)dst[e];
        if (d >= NN) continue;
        unsigned s = (unsigned)src[e];
        if (s >= NN) s = 0;
        int pos = atomicAdd(&cur[d >> 6], 1);
        ebuf[pos] = (int)(s | ((d & 63u) << 17));
    }
}

// ---- per-bucket: count per node, write row_start/dinv, place src-only csr ----
__global__ __launch_bounds__(256) void k_binC(const int* __restrict__ bbase,
                                              const int* __restrict__ tot,
                                              const int* __restrict__ ebuf,
                                              int* __restrict__ row_start,
                                              float* __restrict__ dinv,
                                              int* __restrict__ csr) {
    __shared__ int cnt[64], excl[64], cur[64];
    int b = blockIdx.x, tid = threadIdx.x;
    int n0 = b * 64;
    int base = bbase[b], end = base + tot[b];
    if (tid < 64) cnt[tid] = 0;
    __syncthreads();
    for (int i = base + tid; i < end; i += 256)
        atomicAdd(&cnt[((unsigned)ebuf[i]) >> 17], 1);
    __syncthreads();
    if (tid == 0) {
        int run = 0;
        for (int t = 0; t < 64; ++t) { excl[t] = run; run += cnt[t]; }
    }
    __syncthreads();
    if (tid < 64) {
        int node = n0 + tid;
        if (node < NN) {
            row_start[node] = base + excl[tid];
            dinv[node] = rsqrtf((float)cnt[tid] + 1.0f);
        }
        cur[tid] = base + excl[tid];
    }
    if (b == NBUCK - 1 && tid == 0) row_start[NN] = end;
    __syncthreads();
    for (int i = base + tid; i < end; i += 256) {
        unsigned rec = (unsigned)ebuf[i];
        int pos = atomicAdd(&cur[rec >> 17], 1);
        csr[pos] = (int)(rec & 0x1FFFFu);
    }
}

// ---- layer-1 aggregate: P[n] = bf16( xb[n]*sn + sum w_e*xb[src_e] ) ----
// Scalarized (wave-uniform node -> s_load csr/dinv, saddr gathers), 8-deep MLP,
// packed v_pk_fma_f32 (2 dims per instr), branchless clamped tail.
__global__ __launch_bounds__(256) void k_agg1(const unsigned short* __restrict__ xb,
                                              const float* __restrict__ dinv,
                                              const int* __restrict__ row_start,
                                              const int* __restrict__ csr,
                                              char* __restrict__ P) {
    int node = __builtin_amdgcn_readfirstlane(blockIdx.x * 4 + (threadIdx.x >> 6));
    int lane = threadIdx.x & 63;
    const unsigned int* xw = (const unsigned int*)xb;   // 64 uints per row
    float dv = dinv[node];
    float sn = dv * dv;
    unsigned int sv = xw[node * 64 + lane];
    f32x2 acc;
    acc.x = __uint_as_float(sv << 16) * sn;
    acc.y = __uint_as_float(sv & 0xFFFF0000u) * sn;
    int base = row_start[node], end = row_start[node + 1];
    int i = base;
    int nfull = (end - base) >> 3;
    for (int c = 0; c < nfull; ++c, i += 8) {
        int s[8]; float w[8]; unsigned int v[8];
#pragma unroll
        for (int q = 0; q < 8; ++q) s[q] = csr[i + q];        // contiguous -> s_load_dwordx8
#pragma unroll
        for (int q = 0; q < 8; ++q) w[q] = dinv[s[q]] * dv;   // uniform gathers
#pragma unroll
        for (int q = 0; q < 8; ++q) v[q] = xw[s[q] * 64 + lane];  // 8 gathers in flight
#pragma unroll
        for (int q = 0; q < 8; ++q) {
            f32x2 xv, wv;
            xv.x = __uint_as_float(v[q] << 16);
            xv.y = __uint_as_float(v[q] & 0xFFFF0000u);
            wv.x = w[q]; wv.y = w[q];
            acc = __builtin_elementwise_fma(xv, wv, acc);     // v_pk_fma_f32
        }
    }
    if (i < end) {                    // clamped tail: re-gather last src with w=0
        int last = end - 1;
#pragma unroll
        for (int q = 0; q < 8; ++q) {
            int idx = i + q;
            int cl = (idx < last) ? idx : last;
            int sq = csr[cl];
            float wq = (idx < end) ? dinv[sq] * dv : 0.f;
            unsigned int vq = xw[sq * 64 + lane];
            f32x2 xv, wv;
            xv.x = __uint_as_float(vq << 16);
            xv.y = __uint_as_float(vq & 0xFFFF0000u);
            wv.x = wq; wv.y = wq;
            acc = __builtin_elementwise_fma(xv, wv, acc);
        }
    }
    unsigned int o = (unsigned int)f2b(acc.x) | ((unsigned int)f2b(acc.y) << 16);
    ((unsigned int*)(P + (size_t)node * 256))[lane] = o;
}

// ---- fused GEMM1+GEMM2 (MFMA): t2 = bf16( relu(agg@W1+b1) @ W2 ), in-place ----
__global__ __launch_bounds__(256) void k_gemm12(const float* __restrict__ W1,
                                                const float* __restrict__ b1,
                                                const float* __restrict__ W2,
                                                char* __restrict__ P) {
    __shared__ short Wl1[16384];                    // [ct8][ks4][lane64][j8]
    __shared__ short Wl2[8192];                     // [ct4][ks4][lane64][j8]
    __shared__ __align__(16) short Cl[4][16][128];
    const int tid = threadIdx.x;
    const int w = tid >> 6, lane = tid & 63;
    const int r0 = blockIdx.x * 64;

    for (int i = tid; i < 16384; i += 256) {
        int j = i & 7, l = (i >> 3) & 63, ks = (i >> 9) & 3, ct = i >> 11;
        int k = ks * 32 + ((l >> 4) << 3) + j;
        int c = ct * 16 + (l & 15);
        Wl1[i] = (short)f2b(W1[k * 128 + c]);
    }
    for (int i = tid; i < 8192; i += 256) {
        int j = i & 7, l = (i >> 3) & 63, ks = (i >> 9) & 3, ct = i >> 11;
        int k = ks * 32 + ((l >> 4) << 3) + j;
        int c = ct * 16 + (l & 15);
        Wl2[i] = (short)f2b(W2[k * 64 + c]);
    }
    __syncthreads();

    const int m = r0 + w * 16 + (lane & 15);
    const int quad = lane >> 4;
    const bool mok = (m < NN);
    bf16x8 a[4];
#pragma unroll
    for (int ks = 0; ks < 4; ++ks) {
        if (mok) a[ks] = *(const bf16x8*)(P + (size_t)m * 256 + (ks * 32 + quad * 8) * 2);
        else     a[ks] = bf16x8{0,0,0,0,0,0,0,0};
    }
#pragma unroll
    for (int ct = 0; ct < 8; ++ct) {
        f32x4 c = {0.f, 0.f, 0.f, 0.f};
#pragma unroll
        for (int ks = 0; ks < 4; ++ks) {
            bf16x8 b = *(const bf16x8*)&Wl1[((ct * 4 + ks) * 64 + lane) * 8];
            c = __builtin_amdgcn_mfma_f32_16x16x32_bf16(a[ks], b, c, 0, 0, 0);
        }
        int col = ct * 16 + (lane & 15);
        float bias = b1[col];
#pragma unroll
        for (int r = 0; r < 4; ++r)
            Cl[w][quad * 4 + r][col] = (short)f2b(fmaxf(c[r] + bias, 0.f));
    }
    __syncthreads();
    bf16x8 a2[4];
#pragma unroll
    for (int ks = 0; ks < 4; ++ks)
        a2[ks] = *(const bf16x8*)&Cl[w][lane & 15][ks * 32 + quad * 8];
    __syncthreads();
    short* Ct = &Cl[0][0][0];   // [64 rows][64 cols]
#pragma unroll
    for (int ct = 0; ct < 4; ++ct) {
        f32x4 c = {0.f, 0.f, 0.f, 0.f};
#pragma unroll
        for (int ks = 0; ks < 4; ++ks) {
            bf16x8 b = *(const bf16x8*)&Wl2[((ct * 4 + ks) * 64 + lane) * 8];
            c = __builtin_amdgcn_mfma_f32_16x16x32_bf16(a2[ks], b, c, 0, 0, 0);
        }
        int col = ct * 16 + (lane & 15);
#pragma unroll
        for (int r = 0; r < 4; ++r)
            Ct[(w * 16 + quad * 4 + r) * 64 + col] = (short)f2b(c[r]);
    }
    __syncthreads();
    for (int it = 0; it < 8; ++it) {
        int row = it * 2 + (lane >> 5), u = lane & 31;
        int node = r0 + w * 16 + row;
        if (node < NN)
            *(unsigned int*)(P + (size_t)node * 256 + u * 4) =
                ((const unsigned int*)&Ct[(w * 16 + row) * 64])[u];
    }
}

// ---- layer-2 aggregate + epilogue: out = t2*sn + sum w_e*t2[src] + b2 ----
// Same scalarized 8-deep structure; rows are 128B (64 bf16), 2B/lane loads.
__global__ __launch_bounds__(256) void k_agg2(const float* __restrict__ dinv,
                                              const int* __restrict__ row_start,
                                              const int* __restrict__ csr,
                                              const char* __restrict__ P,
                                              const float* __restrict__ b2,
                                              float* __restrict__ outp) {
    int node = __builtin_amdgcn_readfirstlane(blockIdx.x * 4 + (threadIdx.x >> 6));
    int lane = threadIdx.x & 63;
    const unsigned short* Pw = (const unsigned short*)P;   // 128 ushorts per 256B row
    float dv = dinv[node];
    float sn = dv * dv;
    float acc = b2f(Pw[node * 128 + lane]) * sn;
    int base = row_start[node], end = row_start[node + 1];
    int i = base;
    int nfull = (end - base) >> 3;
    for (int c = 0; c < nfull; ++c, i += 8) {
        int s[8]; float w[8]; unsigned short v[8];
#pragma unroll
        for (int q = 0; q < 8; ++q) s[q] = csr[i + q];
#pragma unroll
        for (int q = 0; q < 8; ++q) w[q] = dinv[s[q]] * dv;
#pragma unroll
        for (int q = 0; q < 8; ++q) v[q] = Pw[s[q] * 128 + lane];
#pragma unroll
        for (int q = 0; q < 8; ++q) acc = fmaf(b2f(v[q]), w[q], acc);
    }
    if (i < end) {
        int last = end - 1;
#pragma unroll
        for (int q = 0; q < 8; ++q) {
            int idx = i + q;
            int cl = (idx < last) ? idx : last;
            int sq = csr[cl];
            float wq = (idx < end) ? dinv[sq] * dv : 0.f;
            acc = fmaf(b2f(Pw[sq * 128 + lane]), wq, acc);
        }
    }
    outp[node * 64 + lane] = acc + b2[lane];
}

extern "C" void kernel_launch(void* const* d_in, const int* in_sizes, int n_in,
                              void* d_out, int out_size, void* d_ws, size_t ws_size,
                              hipStream_t stream) {
    const float* x  = (const float*)d_in[0];
    const int*   ei = (const int*)d_in[1];
    const float* W1 = (const float*)d_in[2];
    const float* b1 = (const float*)d_in[3];
    const float* W2 = (const float*)d_in[4];
    const float* b2 = (const float*)d_in[5];
    float* out = (float*)d_out;
    const int* src = ei;
    const int* dst = ei + NE;

    char* ws = (char*)d_ws;
    unsigned short* xb        = (unsigned short*)(ws + 0);
    char*           P         = ws + 25600000;
    int*            ghist     = (int*)(ws + 25600000);   // overlaps P (dead first)
    int*            boffT     = (int*)(ws + 27200512);
    int*            tot       = (int*)(ws + 28801024);
    int*            bbase     = (int*)(ws + 28807276);
    int*            row_start = (int*)(ws + 51200000);
    float*          dinv      = (float*)(ws + 51600004);
    int*            csr       = (int*)(ws + 52000004);
    int*            ebuf      = (int*)(ws + 58400004);

    k_pre  <<<NBXB + NBH, 256, 0, stream>>>(x, xb, dst, ghist);
    k_scanB<<<(NBUCK + 255) / 256, 256, 0, stream>>>(ghist, boffT, tot);
    k_scanT<<<1, 256, 0, stream>>>(tot, bbase);
    k_place<<<NBH, 256, 0, stream>>>(src, dst, bbase, boffT, ebuf);
    k_binC <<<NBUCK, 256, 0, stream>>>(bbase, tot, ebuf, row_start, dinv, csr);

    k_agg1  <<<NN / 4, 256, 0, stream>>>(xb, dinv, row_start, csr, P);
    k_gemm12<<<NBG, 256, 0, stream>>>(W1, b1, W2, P);
    k_agg2  <<<NN / 4, 256, 0, stream>>>(dinv, row_start, csr, P, b2, out);
}